// Round 9
// baseline (45.329 us; speedup 1.0000x reference)
//
#include <hip/hip_runtime.h>
#include <hip/hip_bf16.h>

#define N_NODES 4096
#define F_DIM   512
#define U_DIM   64
#define H_HEADS 8
#define C_DIM   512   // H*U
#define LRELU_S 0.2f
#define MAXE    128   // mean degree 42, sd 6.4; P(E>128) ~ 1e-25

typedef __attribute__((ext_vector_type(8))) short bf16x8;
typedef __attribute__((ext_vector_type(4))) float f32x4;

__device__ inline unsigned short f2bf(float f) {
  union { float f; unsigned u; } v; v.f = f;
  unsigned r = v.u + 0x7FFFu + ((v.u >> 16) & 1u);  // RTNE
  return (unsigned short)(r >> 16);
}
__device__ inline float bf2f(unsigned short b) {
  union { unsigned u; float f; } v; v.u = ((unsigned)b) << 16;
  return v.f;
}

// ---------------------------------------------------------------------------
// front_kernel:
//  blocks [0, N_NODES): A-row scan -> CSR via BALLOT compaction.
//    Wave w owns contiguous quarter-row [w*1024, (w+1)*1024): 4 coalesced
//    float4 loads/lane, 16 __ballot masks (SGPR, no LDS), per-lane position
//    = mbcnt(mask & lt). ONE barrier (cross-wave offset). No bpermute chain.
//  blocks [N_NODES, +GEMM): h = X@W (bf16 MFMA, 64x64 tile, 4 waves of
//    32x32) + fused logits epilogue -> TRANSPOSED fsT/fnT ([node][head]).
//  Scan blocks first: their HBM stream is the long pole.
// ---------------------------------------------------------------------------
__global__ __launch_bounds__(256) void front_kernel(
    const float* __restrict__ X, const float* __restrict__ W,
    const float* __restrict__ A, const float* __restrict__ a_self,
    const float* __restrict__ a_neigh, unsigned short* __restrict__ hb,
    float* __restrict__ fsT, float* __restrict__ fnT, int* __restrict__ deg,
    unsigned short* __restrict__ nbr) {
  __shared__ unsigned short As[64][72];  // +8 pad: 2-way bank alias only
  __shared__ unsigned short Bs[64][72];
  __shared__ int wsum[4];

  const int t    = threadIdx.x;
  const int lane = t & 63;
  const int w    = t >> 6;

  if ((int)blockIdx.x < N_NODES) {
    // -------- scan branch: ballot compaction, one barrier --------
    const int i = (int)blockIdx.x;
    const float* Aq = A + (size_t)i * N_NODES + w * 1024;
    float4 v0 = *(const float4*)(Aq +   0 + 4 * lane);
    float4 v1 = *(const float4*)(Aq + 256 + 4 * lane);
    float4 v2 = *(const float4*)(Aq + 512 + 4 * lane);
    float4 v3 = *(const float4*)(Aq + 768 + 4 * lane);

    unsigned long long mk[16];
    mk[ 0] = __ballot(v0.x != 0.f); mk[ 1] = __ballot(v0.y != 0.f);
    mk[ 2] = __ballot(v0.z != 0.f); mk[ 3] = __ballot(v0.w != 0.f);
    mk[ 4] = __ballot(v1.x != 0.f); mk[ 5] = __ballot(v1.y != 0.f);
    mk[ 6] = __ballot(v1.z != 0.f); mk[ 7] = __ballot(v1.w != 0.f);
    mk[ 8] = __ballot(v2.x != 0.f); mk[ 9] = __ballot(v2.y != 0.f);
    mk[10] = __ballot(v2.z != 0.f); mk[11] = __ballot(v2.w != 0.f);
    mk[12] = __ballot(v3.x != 0.f); mk[13] = __ballot(v3.y != 0.f);
    mk[14] = __ballot(v3.z != 0.f); mk[15] = __ballot(v3.w != 0.f);

    int cnt = 0;
#pragma unroll
    for (int q = 0; q < 16; ++q) cnt += __popcll(mk[q]);
    if (lane == 0) wsum[w] = cnt;
    __syncthreads();  // the only barrier in the scan path

    int base = 0;
#pragma unroll
    for (int k = 0; k < 4; ++k)
      if (k < w) base += wsum[k];
    const int total = wsum[0] + wsum[1] + wsum[2] + wsum[3];

    const unsigned long long lt  = (1ULL << lane) - 1ULL;
    const unsigned long long bit = 1ULL << lane;
    unsigned short* nrow = nbr + (size_t)i * MAXE;
#pragma unroll
    for (int q = 0; q < 16; ++q) {
      // element index: w*1024 + (q>>2)*256 + 4*lane + (q&3)
      if (mk[q] & bit) {
        const int pos = base + (int)__popcll(mk[q] & lt);
        if (pos < MAXE)
          nrow[pos] =
              (unsigned short)(w * 1024 + (q >> 2) * 256 + 4 * lane + (q & 3));
      }
      base += (int)__popcll(mk[q]);
    }
    if (t == 0) deg[i] = (total > MAXE) ? MAXE : total;
  } else {
    // ---------------- GEMM branch (proven round-6 shape) ----------------
    const int g    = (int)blockIdx.x - N_NODES;
    const int mblk = g & 63;
    const int head = g >> 6;
    const int m0   = mblk * 64;
    const float* Wh = W + (size_t)head * F_DIM * U_DIM;

    const int wr = w >> 1, wc = w & 1;   // wave grid 2x2, wave tile 32x32
    const int arow = t >> 2;             // A-stage row 0..63
    const int akc  = (t & 3) * 16;       // A-stage k offset
    const int bu   = t & 63;             // B-stage u
    const int bjc  = (t >> 6) * 16;      // B-stage k chunk

    f32x4 acc[2][2] = {};

    for (int k0 = 0; k0 < F_DIM; k0 += 64) {
      // stage A: 64x64 fp32 -> bf16, As[m][k]
      {
        const float* src = X + (size_t)(m0 + arow) * F_DIM + k0 + akc;
        float4 f0 = ((const float4*)src)[0];
        float4 f1 = ((const float4*)src)[1];
        float4 f2 = ((const float4*)src)[2];
        float4 f3 = ((const float4*)src)[3];
        bf16x8 u0 = {(short)f2bf(f0.x), (short)f2bf(f0.y), (short)f2bf(f0.z),
                     (short)f2bf(f0.w), (short)f2bf(f1.x), (short)f2bf(f1.y),
                     (short)f2bf(f1.z), (short)f2bf(f1.w)};
        bf16x8 u1 = {(short)f2bf(f2.x), (short)f2bf(f2.y), (short)f2bf(f2.z),
                     (short)f2bf(f2.w), (short)f2bf(f3.x), (short)f2bf(f3.y),
                     (short)f2bf(f3.z), (short)f2bf(f3.w)};
        *(bf16x8*)&As[arow][akc]     = u0;
        *(bf16x8*)&As[arow][akc + 8] = u1;
      }
      // stage B transposed: Bs[u][k] = W[head][k][u]
      {
        float bv[16];
#pragma unroll
        for (int j = 0; j < 16; ++j)
          bv[j] = Wh[(size_t)(k0 + bjc + j) * U_DIM + bu];
        bf16x8 w0 = {(short)f2bf(bv[0]), (short)f2bf(bv[1]), (short)f2bf(bv[2]),
                     (short)f2bf(bv[3]), (short)f2bf(bv[4]), (short)f2bf(bv[5]),
                     (short)f2bf(bv[6]), (short)f2bf(bv[7])};
        bf16x8 w1 = {(short)f2bf(bv[8]),  (short)f2bf(bv[9]),
                     (short)f2bf(bv[10]), (short)f2bf(bv[11]),
                     (short)f2bf(bv[12]), (short)f2bf(bv[13]),
                     (short)f2bf(bv[14]), (short)f2bf(bv[15])};
        *(bf16x8*)&Bs[bu][bjc]     = w0;
        *(bf16x8*)&Bs[bu][bjc + 8] = w1;
      }
      __syncthreads();

      const int r  = lane & 15;
      const int ko = (lane >> 4) * 8;
#pragma unroll
      for (int kk = 0; kk < 2; ++kk) {
        bf16x8 af0 = *(const bf16x8*)&As[wr * 32 + r][kk * 32 + ko];
        bf16x8 af1 = *(const bf16x8*)&As[wr * 32 + 16 + r][kk * 32 + ko];
        bf16x8 bf0 = *(const bf16x8*)&Bs[wc * 32 + r][kk * 32 + ko];
        bf16x8 bf1 = *(const bf16x8*)&Bs[wc * 32 + 16 + r][kk * 32 + ko];
        acc[0][0] = __builtin_amdgcn_mfma_f32_16x16x32_bf16(af0, bf0, acc[0][0], 0, 0, 0);
        acc[0][1] = __builtin_amdgcn_mfma_f32_16x16x32_bf16(af0, bf1, acc[0][1], 0, 0, 0);
        acc[1][0] = __builtin_amdgcn_mfma_f32_16x16x32_bf16(af1, bf0, acc[1][0], 0, 0, 0);
        acc[1][1] = __builtin_amdgcn_mfma_f32_16x16x32_bf16(af1, bf1, acc[1][1], 0, 0, 0);
      }
      __syncthreads();
    }

    // epilogue: write hb (global) + stash bf16 h-tile into As for logits
#pragma unroll
    for (int mi = 0; mi < 2; ++mi) {
#pragma unroll
      for (int ni = 0; ni < 2; ++ni) {
        const int rb = wr * 32 + mi * 16 + (lane >> 4) * 4;  // local row base
        const int cl = wc * 32 + ni * 16 + (lane & 15);      // local col
#pragma unroll
        for (int reg = 0; reg < 4; ++reg) {
          unsigned short hv = f2bf(acc[mi][ni][reg]);
          hb[(size_t)(m0 + rb + reg) * C_DIM + head * U_DIM + cl] = hv;
          As[rb + reg][cl] = hv;
        }
      }
    }
    __syncthreads();
    // fused logits: t<64 -> f_self row t; t in [64,128) -> f_neigh row t-64.
    if (t < 128) {
      const int r = t & 63;
      const float* avec = (t >= 64) ? a_neigh + head * U_DIM
                                    : a_self + head * U_DIM;
      float s = 0.f;
#pragma unroll
      for (int u = 0; u < 64; ++u) s += bf2f(As[r][u]) * avec[u];
      float* dst = (t >= 64) ? fnT : fsT;
      dst[(size_t)(m0 + r) * H_HEADS + head] = s;
    }
  }
}

// ---------------------------------------------------------------------------
// attn_kernel (proven round-6 shape): 4 nodes per block, ONE wave per node.
// Softmax: one 32 B fnT gather per edge covers all 8 heads; shfl reductions.
// Agg: lane owns 8 cols; one uint4 (16 B) gather per edge per lane.
// One __syncthreads total.
// ---------------------------------------------------------------------------
__global__ __launch_bounds__(256) void attn_kernel(
    const unsigned short* __restrict__ hb, const float* __restrict__ fsT,
    const float* __restrict__ fnT, const float* __restrict__ bias,
    const int* __restrict__ deg, const unsigned short* __restrict__ nbr,
    float* __restrict__ out) {
  __shared__ int   eidx[4][MAXE];
  __shared__ float p[4][MAXE][9];  // pad 9: conflict-free read by 8 h-groups

  const int t    = threadIdx.x;
  const int lane = t & 63;
  const int w    = t >> 6;            // node slot in block
  const int i    = blockIdx.x * 4 + w;
  const int E    = deg[i];

  // self logits (all lanes same 32 B -> broadcast)
  float fsv[8];
  {
    float4 a = *(const float4*)(fsT + (size_t)i * H_HEADS);
    float4 b = *(const float4*)(fsT + (size_t)i * H_HEADS + 4);
    fsv[0]=a.x; fsv[1]=a.y; fsv[2]=a.z; fsv[3]=a.w;
    fsv[4]=b.x; fsv[5]=b.y; fsv[6]=b.z; fsv[7]=b.w;
  }

  // pass 1: edge load + raw scores to LDS + per-head local max
  float pmax[8];
#pragma unroll
  for (int h = 0; h < 8; ++h) pmax[h] = -1e30f;
  for (int e = lane; e < E; e += 64) {
    const int j = (int)nbr[(size_t)i * MAXE + e];
    eidx[w][e] = j;
    float4 a = *(const float4*)(fnT + (size_t)j * H_HEADS);
    float4 b = *(const float4*)(fnT + (size_t)j * H_HEADS + 4);
    float fnv[8] = {a.x, a.y, a.z, a.w, b.x, b.y, b.z, b.w};
#pragma unroll
    for (int h = 0; h < 8; ++h) {
      float sc = fsv[h] + fnv[h];
      sc = (sc > 0.f) ? sc : LRELU_S * sc;
      p[w][e][h] = sc;
      pmax[h] = fmaxf(pmax[h], sc);
    }
  }
#pragma unroll
  for (int h = 0; h < 8; ++h)
#pragma unroll
    for (int off = 32; off > 0; off >>= 1)
      pmax[h] = fmaxf(pmax[h], __shfl_xor(pmax[h], off));

  // pass 2: exp + per-head sum (own-lane LDS RAW only)
  float psum[8] = {};
  for (int e = lane; e < E; e += 64) {
#pragma unroll
    for (int h = 0; h < 8; ++h) {
      float ex = __expf(p[w][e][h] - pmax[h]);
      p[w][e][h] = ex;
      psum[h] += ex;
    }
  }
#pragma unroll
  for (int h = 0; h < 8; ++h)
#pragma unroll
    for (int off = 32; off > 0; off >>= 1) psum[h] += __shfl_xor(psum[h], off);

  __syncthreads();  // p/eidx cross-lane visibility

  // aggregation: lane owns cols 8*lane..8*lane+7 (head hl = lane>>3)
  const int cbase = 8 * lane;
  const int hl = lane >> 3;
  float acc[8] = {};
  for (int e = 0; e < E; ++e) {
    const int j = eidx[w][e];                 // broadcast LDS read
    uint4 v = *(const uint4*)(hb + (size_t)j * C_DIM + cbase);
    const float pe = p[w][e][hl];             // conflict-free LDS read
    acc[0] += pe * bf2f((unsigned short)(v.x & 0xFFFFu));
    acc[1] += pe * bf2f((unsigned short)(v.x >> 16));
    acc[2] += pe * bf2f((unsigned short)(v.y & 0xFFFFu));
    acc[3] += pe * bf2f((unsigned short)(v.y >> 16));
    acc[4] += pe * bf2f((unsigned short)(v.z & 0xFFFFu));
    acc[5] += pe * bf2f((unsigned short)(v.z >> 16));
    acc[6] += pe * bf2f((unsigned short)(v.w & 0xFFFFu));
    acc[7] += pe * bf2f((unsigned short)(v.w >> 16));
  }
  // select 1/sum for this lane's head without runtime reg-array indexing
  float sum = psum[0];
#pragma unroll
  for (int h = 1; h < 8; ++h)
    if (hl == h) sum = psum[h];
  const float inv = 1.0f / sum;

  float4 b0 = *(const float4*)(bias + cbase);
  float4 b1 = *(const float4*)(bias + cbase + 4);
  float4 o0, o1;
  o0.x = fmaxf(acc[0] * inv + b0.x, 0.f);
  o0.y = fmaxf(acc[1] * inv + b0.y, 0.f);
  o0.z = fmaxf(acc[2] * inv + b0.z, 0.f);
  o0.w = fmaxf(acc[3] * inv + b0.w, 0.f);
  o1.x = fmaxf(acc[4] * inv + b1.x, 0.f);
  o1.y = fmaxf(acc[5] * inv + b1.y, 0.f);
  o1.z = fmaxf(acc[6] * inv + b1.z, 0.f);
  o1.w = fmaxf(acc[7] * inv + b1.w, 0.f);
  *(float4*)(out + (size_t)i * C_DIM + cbase)     = o0;
  *(float4*)(out + (size_t)i * C_DIM + cbase + 4) = o1;
}

// ---------------------------------------------------------------------------
extern "C" void kernel_launch(void* const* d_in, const int* in_sizes, int n_in,
                              void* d_out, int out_size, void* d_ws,
                              size_t ws_size, hipStream_t stream) {
  const float* X       = (const float*)d_in[0];
  // d_in[1] = out_indices (unused: final_layer=False returns all nodes)
  const float* A       = (const float*)d_in[2];
  const float* W       = (const float*)d_in[3];
  const float* a_self  = (const float*)d_in[4];
  const float* a_neigh = (const float*)d_in[5];
  const float* bias    = (const float*)d_in[6];
  float* out = (float*)d_out;

  unsigned short* hb = (unsigned short*)d_ws;               // N*C bf16 (4 MB)
  float* fsT = (float*)(hb + (size_t)N_NODES * C_DIM);      // N*H f32
  float* fnT = fsT + (size_t)H_HEADS * N_NODES;             // N*H f32
  int* deg   = (int*)(fnT + (size_t)H_HEADS * N_NODES);     // N int
  unsigned short* nbr = (unsigned short*)(deg + N_NODES);   // N*MAXE ushort

  front_kernel<<<N_NODES + 512, 256, 0, stream>>>(
      X, W, A, a_self, a_neigh, hb, fsT, fnT, deg, nbr);

  attn_kernel<<<N_NODES / 4, 256, 0, stream>>>(hb, fsT, fnT, bias, deg, nbr,
                                               out);
}

// Round 10
// 41.540 us; speedup vs baseline: 1.0912x; 1.0912x over previous
//
#include <hip/hip_runtime.h>
#include <hip/hip_bf16.h>

#define N_NODES 4096
#define F_DIM   512
#define U_DIM   64
#define H_HEADS 8
#define C_DIM   512   // H*U
#define LRELU_S 0.2f
#define MAXE    128   // mean degree 42, sd 6.4; P(E>128) ~ 1e-25
#define GEMM_BLOCKS 512  // 64 m-blocks x 8 heads; FIRST in grid (R6 order)

typedef __attribute__((ext_vector_type(8))) short bf16x8;
typedef __attribute__((ext_vector_type(4))) float f32x4;

__device__ inline unsigned short f2bf(float f) {
  union { float f; unsigned u; } v; v.f = f;
  unsigned r = v.u + 0x7FFFu + ((v.u >> 16) & 1u);  // RTNE
  return (unsigned short)(r >> 16);
}
__device__ inline float bf2f(unsigned short b) {
  union { unsigned u; float f; } v; v.u = ((unsigned)b) << 16;
  return v.f;
}

// ---------------------------------------------------------------------------
// front_kernel (R6 structure, single change: ballot-compaction scan):
//  blocks [0, GEMM_BLOCKS): h = X@W (bf16 MFMA, 64x64 tile, 4 waves of
//    32x32) + fused logits epilogue -> TRANSPOSED fsT/fnT ([node][head]).
//  blocks [GEMM_BLOCKS, +N_NODES): A-row scan -> CSR via BALLOT compaction.
//    Wave w owns contiguous quarter-row; 16 __ballot masks (SGPR), per-lane
//    position = popcll(mask & lt); ONE barrier (cross-wave offsets).
// ---------------------------------------------------------------------------
__global__ __launch_bounds__(256) void front_kernel(
    const float* __restrict__ X, const float* __restrict__ W,
    const float* __restrict__ A, const float* __restrict__ a_self,
    const float* __restrict__ a_neigh, unsigned short* __restrict__ hb,
    float* __restrict__ fsT, float* __restrict__ fnT, int* __restrict__ deg,
    unsigned short* __restrict__ nbr) {
  __shared__ unsigned short As[64][72];  // +8 pad: 2-way bank alias only
  __shared__ unsigned short Bs[64][72];
  __shared__ int wsum[4];

  const int t    = threadIdx.x;
  const int lane = t & 63;
  const int w    = t >> 6;

  if ((int)blockIdx.x < GEMM_BLOCKS) {
    // ---------------- GEMM branch (proven round-6 shape) ----------------
    const int mblk = blockIdx.x & 63;
    const int head = blockIdx.x >> 6;
    const int m0   = mblk * 64;
    const float* Wh = W + (size_t)head * F_DIM * U_DIM;

    const int wr = w >> 1, wc = w & 1;   // wave grid 2x2, wave tile 32x32
    const int arow = t >> 2;             // A-stage row 0..63
    const int akc  = (t & 3) * 16;       // A-stage k offset
    const int bu   = t & 63;             // B-stage u
    const int bjc  = (t >> 6) * 16;      // B-stage k chunk

    f32x4 acc[2][2] = {};

    for (int k0 = 0; k0 < F_DIM; k0 += 64) {
      // stage A: 64x64 fp32 -> bf16, As[m][k]
      {
        const float* src = X + (size_t)(m0 + arow) * F_DIM + k0 + akc;
        float4 f0 = ((const float4*)src)[0];
        float4 f1 = ((const float4*)src)[1];
        float4 f2 = ((const float4*)src)[2];
        float4 f3 = ((const float4*)src)[3];
        bf16x8 u0 = {(short)f2bf(f0.x), (short)f2bf(f0.y), (short)f2bf(f0.z),
                     (short)f2bf(f0.w), (short)f2bf(f1.x), (short)f2bf(f1.y),
                     (short)f2bf(f1.z), (short)f2bf(f1.w)};
        bf16x8 u1 = {(short)f2bf(f2.x), (short)f2bf(f2.y), (short)f2bf(f2.z),
                     (short)f2bf(f2.w), (short)f2bf(f3.x), (short)f2bf(f3.y),
                     (short)f2bf(f3.z), (short)f2bf(f3.w)};
        *(bf16x8*)&As[arow][akc]     = u0;
        *(bf16x8*)&As[arow][akc + 8] = u1;
      }
      // stage B transposed: Bs[u][k] = W[head][k][u]
      {
        float bv[16];
#pragma unroll
        for (int j = 0; j < 16; ++j)
          bv[j] = Wh[(size_t)(k0 + bjc + j) * U_DIM + bu];
        bf16x8 w0 = {(short)f2bf(bv[0]), (short)f2bf(bv[1]), (short)f2bf(bv[2]),
                     (short)f2bf(bv[3]), (short)f2bf(bv[4]), (short)f2bf(bv[5]),
                     (short)f2bf(bv[6]), (short)f2bf(bv[7])};
        bf16x8 w1 = {(short)f2bf(bv[8]),  (short)f2bf(bv[9]),
                     (short)f2bf(bv[10]), (short)f2bf(bv[11]),
                     (short)f2bf(bv[12]), (short)f2bf(bv[13]),
                     (short)f2bf(bv[14]), (short)f2bf(bv[15])};
        *(bf16x8*)&Bs[bu][bjc]     = w0;
        *(bf16x8*)&Bs[bu][bjc + 8] = w1;
      }
      __syncthreads();

      const int r  = lane & 15;
      const int ko = (lane >> 4) * 8;
#pragma unroll
      for (int kk = 0; kk < 2; ++kk) {
        bf16x8 af0 = *(const bf16x8*)&As[wr * 32 + r][kk * 32 + ko];
        bf16x8 af1 = *(const bf16x8*)&As[wr * 32 + 16 + r][kk * 32 + ko];
        bf16x8 bf0 = *(const bf16x8*)&Bs[wc * 32 + r][kk * 32 + ko];
        bf16x8 bf1 = *(const bf16x8*)&Bs[wc * 32 + 16 + r][kk * 32 + ko];
        acc[0][0] = __builtin_amdgcn_mfma_f32_16x16x32_bf16(af0, bf0, acc[0][0], 0, 0, 0);
        acc[0][1] = __builtin_amdgcn_mfma_f32_16x16x32_bf16(af0, bf1, acc[0][1], 0, 0, 0);
        acc[1][0] = __builtin_amdgcn_mfma_f32_16x16x32_bf16(af1, bf0, acc[1][0], 0, 0, 0);
        acc[1][1] = __builtin_amdgcn_mfma_f32_16x16x32_bf16(af1, bf1, acc[1][1], 0, 0, 0);
      }
      __syncthreads();
    }

    // epilogue: write hb (global) + stash bf16 h-tile into As for logits
#pragma unroll
    for (int mi = 0; mi < 2; ++mi) {
#pragma unroll
      for (int ni = 0; ni < 2; ++ni) {
        const int rb = wr * 32 + mi * 16 + (lane >> 4) * 4;  // local row base
        const int cl = wc * 32 + ni * 16 + (lane & 15);      // local col
#pragma unroll
        for (int reg = 0; reg < 4; ++reg) {
          unsigned short hv = f2bf(acc[mi][ni][reg]);
          hb[(size_t)(m0 + rb + reg) * C_DIM + head * U_DIM + cl] = hv;
          As[rb + reg][cl] = hv;
        }
      }
    }
    __syncthreads();
    // fused logits: t<64 -> f_self row t; t in [64,128) -> f_neigh row t-64.
    if (t < 128) {
      const int r = t & 63;
      const float* avec = (t >= 64) ? a_neigh + head * U_DIM
                                    : a_self + head * U_DIM;
      float s = 0.f;
#pragma unroll
      for (int u = 0; u < 64; ++u) s += bf2f(As[r][u]) * avec[u];
      float* dst = (t >= 64) ? fnT : fsT;
      dst[(size_t)(m0 + r) * H_HEADS + head] = s;
    }
  } else {
    // -------- scan branch: ballot compaction, one barrier --------
    const int i = (int)blockIdx.x - GEMM_BLOCKS;
    const float* Aq = A + (size_t)i * N_NODES + w * 1024;
    float4 v0 = *(const float4*)(Aq +   0 + 4 * lane);
    float4 v1 = *(const float4*)(Aq + 256 + 4 * lane);
    float4 v2 = *(const float4*)(Aq + 512 + 4 * lane);
    float4 v3 = *(const float4*)(Aq + 768 + 4 * lane);

    unsigned long long mk[16];
    mk[ 0] = __ballot(v0.x != 0.f); mk[ 1] = __ballot(v0.y != 0.f);
    mk[ 2] = __ballot(v0.z != 0.f); mk[ 3] = __ballot(v0.w != 0.f);
    mk[ 4] = __ballot(v1.x != 0.f); mk[ 5] = __ballot(v1.y != 0.f);
    mk[ 6] = __ballot(v1.z != 0.f); mk[ 7] = __ballot(v1.w != 0.f);
    mk[ 8] = __ballot(v2.x != 0.f); mk[ 9] = __ballot(v2.y != 0.f);
    mk[10] = __ballot(v2.z != 0.f); mk[11] = __ballot(v2.w != 0.f);
    mk[12] = __ballot(v3.x != 0.f); mk[13] = __ballot(v3.y != 0.f);
    mk[14] = __ballot(v3.z != 0.f); mk[15] = __ballot(v3.w != 0.f);

    int cnt = 0;
#pragma unroll
    for (int q = 0; q < 16; ++q) cnt += __popcll(mk[q]);
    if (lane == 0) wsum[w] = cnt;
    __syncthreads();  // the only barrier in the scan path

    int base = 0;
#pragma unroll
    for (int k = 0; k < 4; ++k)
      if (k < w) base += wsum[k];
    const int total = wsum[0] + wsum[1] + wsum[2] + wsum[3];

    const unsigned long long lt  = (lane == 63) ? 0x7FFFFFFFFFFFFFFFULL
                                                : ((1ULL << lane) - 1ULL);
    const unsigned long long bit = 1ULL << lane;
    unsigned short* nrow = nbr + (size_t)i * MAXE;
#pragma unroll
    for (int q = 0; q < 16; ++q) {
      // element index: w*1024 + (q>>2)*256 + 4*lane + (q&3)
      if (mk[q] & bit) {
        const int pos = base + (int)__popcll(mk[q] & lt);
        if (pos < MAXE)
          nrow[pos] =
              (unsigned short)(w * 1024 + (q >> 2) * 256 + 4 * lane + (q & 3));
      }
      base += (int)__popcll(mk[q]);
    }
    if (t == 0) deg[i] = (total > MAXE) ? MAXE : total;
  }
}

// ---------------------------------------------------------------------------
// attn_kernel (round-6 champion, unchanged): 4 nodes per block, ONE wave per
// node. Softmax: one 32 B fnT gather per edge covers all 8 heads; shfl
// reductions. Agg: lane owns 8 cols; one uint4 gather per edge per lane.
// One __syncthreads total.
// ---------------------------------------------------------------------------
__global__ __launch_bounds__(256) void attn_kernel(
    const unsigned short* __restrict__ hb, const float* __restrict__ fsT,
    const float* __restrict__ fnT, const float* __restrict__ bias,
    const int* __restrict__ deg, const unsigned short* __restrict__ nbr,
    float* __restrict__ out) {
  __shared__ int   eidx[4][MAXE];
  __shared__ float p[4][MAXE][9];  // pad 9: conflict-free read by 8 h-groups

  const int t    = threadIdx.x;
  const int lane = t & 63;
  const int w    = t >> 6;            // node slot in block
  const int i    = blockIdx.x * 4 + w;
  const int E    = deg[i];

  // self logits (all lanes same 32 B -> broadcast)
  float fsv[8];
  {
    float4 a = *(const float4*)(fsT + (size_t)i * H_HEADS);
    float4 b = *(const float4*)(fsT + (size_t)i * H_HEADS + 4);
    fsv[0]=a.x; fsv[1]=a.y; fsv[2]=a.z; fsv[3]=a.w;
    fsv[4]=b.x; fsv[5]=b.y; fsv[6]=b.z; fsv[7]=b.w;
  }

  // pass 1: edge load + raw scores to LDS + per-head local max
  float pmax[8];
#pragma unroll
  for (int h = 0; h < 8; ++h) pmax[h] = -1e30f;
  for (int e = lane; e < E; e += 64) {
    const int j = (int)nbr[(size_t)i * MAXE + e];
    eidx[w][e] = j;
    float4 a = *(const float4*)(fnT + (size_t)j * H_HEADS);
    float4 b = *(const float4*)(fnT + (size_t)j * H_HEADS + 4);
    float fnv[8] = {a.x, a.y, a.z, a.w, b.x, b.y, b.z, b.w};
#pragma unroll
    for (int h = 0; h < 8; ++h) {
      float sc = fsv[h] + fnv[h];
      sc = (sc > 0.f) ? sc : LRELU_S * sc;
      p[w][e][h] = sc;
      pmax[h] = fmaxf(pmax[h], sc);
    }
  }
#pragma unroll
  for (int h = 0; h < 8; ++h)
#pragma unroll
    for (int off = 32; off > 0; off >>= 1)
      pmax[h] = fmaxf(pmax[h], __shfl_xor(pmax[h], off));

  // pass 2: exp + per-head sum (own-lane LDS RAW only)
  float psum[8] = {};
  for (int e = lane; e < E; e += 64) {
#pragma unroll
    for (int h = 0; h < 8; ++h) {
      float ex = __expf(p[w][e][h] - pmax[h]);
      p[w][e][h] = ex;
      psum[h] += ex;
    }
  }
#pragma unroll
  for (int h = 0; h < 8; ++h)
#pragma unroll
    for (int off = 32; off > 0; off >>= 1) psum[h] += __shfl_xor(psum[h], off);

  __syncthreads();  // p/eidx cross-lane visibility

  // aggregation: lane owns cols 8*lane..8*lane+7 (head hl = lane>>3)
  const int cbase = 8 * lane;
  const int hl = lane >> 3;
  float acc[8] = {};
  for (int e = 0; e < E; ++e) {
    const int j = eidx[w][e];                 // broadcast LDS read
    uint4 v = *(const uint4*)(hb + (size_t)j * C_DIM + cbase);
    const float pe = p[w][e][hl];             // conflict-free LDS read
    acc[0] += pe * bf2f((unsigned short)(v.x & 0xFFFFu));
    acc[1] += pe * bf2f((unsigned short)(v.x >> 16));
    acc[2] += pe * bf2f((unsigned short)(v.y & 0xFFFFu));
    acc[3] += pe * bf2f((unsigned short)(v.y >> 16));
    acc[4] += pe * bf2f((unsigned short)(v.z & 0xFFFFu));
    acc[5] += pe * bf2f((unsigned short)(v.z >> 16));
    acc[6] += pe * bf2f((unsigned short)(v.w & 0xFFFFu));
    acc[7] += pe * bf2f((unsigned short)(v.w >> 16));
  }
  // select 1/sum for this lane's head without runtime reg-array indexing
  float sum = psum[0];
#pragma unroll
  for (int h = 1; h < 8; ++h)
    if (hl == h) sum = psum[h];
  const float inv = 1.0f / sum;

  float4 b0 = *(const float4*)(bias + cbase);
  float4 b1 = *(const float4*)(bias + cbase + 4);
  float4 o0, o1;
  o0.x = fmaxf(acc[0] * inv + b0.x, 0.f);
  o0.y = fmaxf(acc[1] * inv + b0.y, 0.f);
  o0.z = fmaxf(acc[2] * inv + b0.z, 0.f);
  o0.w = fmaxf(acc[3] * inv + b0.w, 0.f);
  o1.x = fmaxf(acc[4] * inv + b1.x, 0.f);
  o1.y = fmaxf(acc[5] * inv + b1.y, 0.f);
  o1.z = fmaxf(acc[6] * inv + b1.z, 0.f);
  o1.w = fmaxf(acc[7] * inv + b1.w, 0.f);
  *(float4*)(out + (size_t)i * C_DIM + cbase)     = o0;
  *(float4*)(out + (size_t)i * C_DIM + cbase + 4) = o1;
}

// ---------------------------------------------------------------------------
extern "C" void kernel_launch(void* const* d_in, const int* in_sizes, int n_in,
                              void* d_out, int out_size, void* d_ws,
                              size_t ws_size, hipStream_t stream) {
  const float* X       = (const float*)d_in[0];
  // d_in[1] = out_indices (unused: final_layer=False returns all nodes)
  const float* A       = (const float*)d_in[2];
  const float* W       = (const float*)d_in[3];
  const float* a_self  = (const float*)d_in[4];
  const float* a_neigh = (const float*)d_in[5];
  const float* bias    = (const float*)d_in[6];
  float* out = (float*)d_out;

  unsigned short* hb = (unsigned short*)d_ws;               // N*C bf16 (4 MB)
  float* fsT = (float*)(hb + (size_t)N_NODES * C_DIM);      // N*H f32
  float* fnT = fsT + (size_t)H_HEADS * N_NODES;             // N*H f32
  int* deg   = (int*)(fnT + (size_t)H_HEADS * N_NODES);     // N int
  unsigned short* nbr = (unsigned short*)(deg + N_NODES);   // N*MAXE ushort

  front_kernel<<<GEMM_BLOCKS + N_NODES, 256, 0, stream>>>(
      X, W, A, a_self, a_neigh, hb, fsT, fnT, deg, nbr);

  attn_kernel<<<N_NODES / 4, 256, 0, stream>>>(hb, fsT, fnT, bias, deg, nbr,
                                               out);
}